// Round 1
// baseline (106.322 us; speedup 1.0000x reference)
//
#include <hip/hip_runtime.h>
#include <math.h>

#define T_STEPS 1000
#define BETA_1f 0.0001f
#define BETA_Tf 0.02f

// --- Kernel 1: per-batch diffusion scale factors (sequential cumprod, matches jnp.cumprod order) ---
__global__ void precompute_scales(const int* __restrict__ t, float* __restrict__ ws, int B) {
    int i = threadIdx.x;
    if (i >= B) return;
    int tv = t[i];
    const float step = (BETA_Tf - BETA_1f) / (float)(T_STEPS - 1);
    float prod = 1.0f;
    for (int j = 0; j <= tv; ++j) {
        float beta = BETA_1f + step * (float)j;
        prod *= (1.0f - beta);
    }
    ws[i]     = sqrtf(prod);          // sqrt(alphas_bar[t])
    ws[B + i] = sqrtf(1.0f - prod);   // sqrt(1 - alphas_bar[t])
}

// --- Kernel 2: fused haar-dwt -> d_t -> 8->4 matvec -> squared-error sum ---
// Layout: x_0 (B,2,512,512), noise (B,4,256,256), output pixels (B,256,256).
// Each thread handles 2 adjacent output pixels (w = 2*w2, 2*w2+1):
//   x_0 loads: 4x float4 (16B/lane, coalesced); noise: 4x float2.
__global__ __launch_bounds__(256) void fused_loss_kernel(
    const float* __restrict__ x0,
    const float* __restrict__ noise,
    const float* __restrict__ Wm,     // (4,8) row-major [o][c]
    const float* __restrict__ bias,   // (4,)
    const float* __restrict__ temb,   // (1000,4)
    const int*   __restrict__ t,      // (B,)
    const float* __restrict__ scales, // ws: [0..B) sqrt_ab, [B..2B) sqrt_omab
    float* __restrict__ out,
    int B)
{
    const int idx = blockIdx.x * blockDim.x + threadIdx.x;
    // per-batch: 256 rows x 128 thread-cols = 32768 threads
    const int b   = idx >> 15;
    const int rem = idx & 32767;
    const int h   = rem >> 7;
    const int w2  = rem & 127;

    // uniform-per-batch scalars
    const float sab   = scales[b];
    const float somab = scales[B + b];
    const int   tv    = t[b];
    float base[4];
#pragma unroll
    for (int o = 0; o < 4; ++o) base[o] = bias[o] + temb[tv * 4 + o];

    // W into registers (uniform address -> scalar loads, L2/L1 cached)
    float w[32];
#pragma unroll
    for (int i = 0; i < 32; ++i) w[i] = Wm[i];

    // --- loads ---
    const float* x0b = x0 + (size_t)b * 2 * 512 * 512;
    const float* x1b = x0b + 512 * 512;
    const int roff0 = (2 * h) * 512 + 4 * w2;
    const int roff1 = roff0 + 512;
    const float4 ct0 = *(const float4*)(x0b + roff0);
    const float4 ct1 = *(const float4*)(x0b + roff1);
    const float4 cb0 = *(const float4*)(x1b + roff0);
    const float4 cb1 = *(const float4*)(x1b + roff1);

    const float* nb = noise + (size_t)b * 4 * 256 * 256 + h * 256 + 2 * w2;
    const float2 n0 = *(const float2*)(nb + 0 * 65536);
    const float2 n1 = *(const float2*)(nb + 1 * 65536);
    const float2 n2 = *(const float2*)(nb + 2 * 65536);
    const float2 n3 = *(const float2*)(nb + 3 * 65536);

    float local = 0.0f;

#pragma unroll
    for (int p = 0; p < 2; ++p) {
        // 2x2 quad for this output pixel
        const float ca_ = p ? ct0.z : ct0.x;
        const float cb_ = p ? ct0.w : ct0.y;
        const float cc_ = p ? ct1.z : ct1.x;
        const float cd_ = p ? ct1.w : ct1.y;
        const float ba_ = p ? cb0.z : cb0.x;
        const float bb_ = p ? cb0.w : cb0.y;
        const float bc_ = p ? cb1.z : cb1.x;
        const float bd_ = p ? cb1.w : cb1.y;

        // haar DWT, ct channel
        const float tA = (ca_ + cb_ + cc_ + cd_) * 0.5f;
        const float tH = (ca_ + cb_ - cc_ - cd_) * 0.5f;
        const float tV = (ca_ - cb_ + cc_ - cd_) * 0.5f;
        const float tD = (ca_ - cb_ - cc_ + cd_) * 0.5f;
        // haar DWT, cbct channel
        const float gA = (ba_ + bb_ + bc_ + bd_) * 0.5f;
        const float gH = (ba_ + bb_ - bc_ - bd_) * 0.5f;
        const float gV = (ba_ - bb_ + bc_ - bd_) * 0.5f;
        const float gD = (ba_ - bb_ - bc_ + bd_) * 0.5f;

        const float nz0 = p ? n0.y : n0.x;
        const float nz1 = p ? n1.y : n1.x;
        const float nz2 = p ? n2.y : n2.x;
        const float nz3 = p ? n3.y : n3.x;

        float mi[8];
        mi[0] = sab * (tA - gA) + somab * nz0;
        mi[1] = sab * (tH - gH) + somab * nz1;
        mi[2] = sab * (tV - gV) + somab * nz2;
        mi[3] = sab * (tD - gD) + somab * nz3;
        mi[4] = gA; mi[5] = gH; mi[6] = gV; mi[7] = gD;

        const float nz[4] = { nz0, nz1, nz2, nz3 };
#pragma unroll
        for (int o = 0; o < 4; ++o) {
            float e = base[o];
#pragma unroll
            for (int c = 0; c < 8; ++c) e = fmaf(w[o * 8 + c], mi[c], e);
            const float d = e - nz[o];
            local = fmaf(d, d, local);
        }
    }

    // --- block reduction ---
#pragma unroll
    for (int off = 32; off > 0; off >>= 1) local += __shfl_down(local, off);
    __shared__ float ssum[4];
    const int lane = threadIdx.x & 63;
    const int wid  = threadIdx.x >> 6;
    if (lane == 0) ssum[wid] = local;
    __syncthreads();
    if (threadIdx.x == 0) {
        atomicAdd(out, ssum[0] + ssum[1] + ssum[2] + ssum[3]);
    }
}

extern "C" void kernel_launch(void* const* d_in, const int* in_sizes, int n_in,
                              void* d_out, int out_size, void* d_ws, size_t ws_size,
                              hipStream_t stream) {
    const float* x0    = (const float*)d_in[0];
    const float* noise = (const float*)d_in[1];
    const float* Wm    = (const float*)d_in[2];
    const float* bias  = (const float*)d_in[3];
    const float* temb  = (const float*)d_in[4];
    const int*   t     = (const int*)d_in[5];
    float* out = (float*)d_out;
    float* ws  = (float*)d_ws;

    const int B = in_sizes[0] / (2 * 512 * 512);   // 32

    hipMemsetAsync(d_out, 0, (size_t)out_size * sizeof(float), stream);
    precompute_scales<<<1, 64, 0, stream>>>(t, ws, B);

    const int total  = B * 256 * 128;              // one thread per 2 output pixels
    const int blocks = total / 256;                // 4096
    fused_loss_kernel<<<blocks, 256, 0, stream>>>(x0, noise, Wm, bias, temb, t, ws, out, B);
}

// Round 2
// 24.076 us; speedup vs baseline: 4.4161x; 4.4161x over previous
//
#include <hip/hip_runtime.h>
#include <math.h>

#define T_STEPS 1000
#define BETA_1f 0.0001f
#define BETA_Tf 0.02f

// Fused: haar-dwt -> d_t -> 8->4 matvec -> squared-error, per-block partial sum to ws.
// Layout: x_0 (B,2,512,512), noise (B,4,256,256). Output pixel grid per batch: 256x256.
// Each thread: 4 adjacent output pixels -> 12x float4 loads (192 B, all 16B coalesced).
__global__ __launch_bounds__(256) void fused_loss_kernel(
    const float* __restrict__ x0,
    const float* __restrict__ noise,
    const float* __restrict__ Wm,     // (4,8) row-major [o][c]
    const float* __restrict__ bias,   // (4,)
    const float* __restrict__ temb,   // (1000,4)
    const int*   __restrict__ t,      // (B,)
    float* __restrict__ partials)     // ws: one float per block
{
    const int idx = blockIdx.x * blockDim.x + threadIdx.x;
    // per batch: 256 rows x 64 thread-cols = 16384 threads
    const int b   = idx >> 14;
    const int rem = idx & 16383;
    const int h   = rem >> 6;
    const int w4  = rem & 63;
    const int lane = threadIdx.x & 63;

    // ---- per-batch diffusion scales, computed wave-parallel (redundant per wave, ~150 cy) ----
    const int tv = t[b];               // uniform within block
    const float step = (BETA_Tf - BETA_1f) / (float)(T_STEPS - 1);
    float prod = 1.0f;
    {
        const int j0 = lane * 16;      // 64 lanes x 16 = 1024 >= T
#pragma unroll
        for (int k = 0; k < 16; ++k) {
            const int j = j0 + k;
            const float f = (j <= tv && j < T_STEPS) ? (1.0f - (BETA_1f + step * (float)j)) : 1.0f;
            prod *= f;
        }
#pragma unroll
        for (int off = 32; off > 0; off >>= 1) prod *= __shfl_xor(prod, off);
    }
    const float sab   = sqrtf(prod);
    const float somab = sqrtf(1.0f - prod);

    float base[4];
#pragma unroll
    for (int o = 0; o < 4; ++o) base[o] = bias[o] + temb[tv * 4 + o];

    // W into registers (uniform address -> scalar loads)
    float w[32];
#pragma unroll
    for (int i = 0; i < 32; ++i) w[i] = Wm[i];

    // ---- loads: 2 input rows x 8 cols x 2 channels of x0, 4 channels x 4 cols of noise ----
    const float* x0b = x0 + (size_t)b * 2 * 512 * 512;
    const float* x1b = x0b + 512 * 512;
    const int roff0 = (2 * h) * 512 + 8 * w4;
    const int roff1 = roff0 + 512;

    float ct_r0[8], ct_r1[8], cb_r0[8], cb_r1[8];
    *(float4*)&ct_r0[0] = *(const float4*)(x0b + roff0);
    *(float4*)&ct_r0[4] = *(const float4*)(x0b + roff0 + 4);
    *(float4*)&ct_r1[0] = *(const float4*)(x0b + roff1);
    *(float4*)&ct_r1[4] = *(const float4*)(x0b + roff1 + 4);
    *(float4*)&cb_r0[0] = *(const float4*)(x1b + roff0);
    *(float4*)&cb_r0[4] = *(const float4*)(x1b + roff0 + 4);
    *(float4*)&cb_r1[0] = *(const float4*)(x1b + roff1);
    *(float4*)&cb_r1[4] = *(const float4*)(x1b + roff1 + 4);

    const float* nb = noise + (size_t)b * 4 * 65536 + h * 256 + 4 * w4;
    float nz[4][4];
    *(float4*)&nz[0][0] = *(const float4*)(nb + 0 * 65536);
    *(float4*)&nz[1][0] = *(const float4*)(nb + 1 * 65536);
    *(float4*)&nz[2][0] = *(const float4*)(nb + 2 * 65536);
    *(float4*)&nz[3][0] = *(const float4*)(nb + 3 * 65536);

    float local = 0.0f;

#pragma unroll
    for (int p = 0; p < 4; ++p) {
        const float ca_ = ct_r0[2 * p],     cb_ = ct_r0[2 * p + 1];
        const float cc_ = ct_r1[2 * p],     cd_ = ct_r1[2 * p + 1];
        const float ba_ = cb_r0[2 * p],     bb_ = cb_r0[2 * p + 1];
        const float bc_ = cb_r1[2 * p],     bd_ = cb_r1[2 * p + 1];

        const float tA = (ca_ + cb_ + cc_ + cd_) * 0.5f;
        const float tH = (ca_ + cb_ - cc_ - cd_) * 0.5f;
        const float tV = (ca_ - cb_ + cc_ - cd_) * 0.5f;
        const float tD = (ca_ - cb_ - cc_ + cd_) * 0.5f;
        const float gA = (ba_ + bb_ + bc_ + bd_) * 0.5f;
        const float gH = (ba_ + bb_ - bc_ - bd_) * 0.5f;
        const float gV = (ba_ - bb_ + bc_ - bd_) * 0.5f;
        const float gD = (ba_ - bb_ - bc_ + bd_) * 0.5f;

        float mi[8];
        mi[0] = sab * (tA - gA) + somab * nz[0][p];
        mi[1] = sab * (tH - gH) + somab * nz[1][p];
        mi[2] = sab * (tV - gV) + somab * nz[2][p];
        mi[3] = sab * (tD - gD) + somab * nz[3][p];
        mi[4] = gA; mi[5] = gH; mi[6] = gV; mi[7] = gD;

#pragma unroll
        for (int o = 0; o < 4; ++o) {
            float e = base[o];
#pragma unroll
            for (int c = 0; c < 8; ++c) e = fmaf(w[o * 8 + c], mi[c], e);
            const float d = e - nz[o][p];
            local = fmaf(d, d, local);
        }
    }

    // ---- block reduction -> one partial per block (no atomics) ----
#pragma unroll
    for (int off = 32; off > 0; off >>= 1) local += __shfl_down(local, off);
    __shared__ float ssum[4];
    const int wid = threadIdx.x >> 6;
    if (lane == 0) ssum[wid] = local;
    __syncthreads();
    if (threadIdx.x == 0) {
        partials[blockIdx.x] = ssum[0] + ssum[1] + ssum[2] + ssum[3];
    }
}

__global__ __launch_bounds__(256) void final_reduce_kernel(
    const float* __restrict__ partials, float* __restrict__ out, int n)
{
    float local = 0.0f;
    for (int i = threadIdx.x; i < n; i += 256) local += partials[i];
#pragma unroll
    for (int off = 32; off > 0; off >>= 1) local += __shfl_down(local, off);
    __shared__ float ssum[4];
    const int lane = threadIdx.x & 63;
    const int wid  = threadIdx.x >> 6;
    if (lane == 0) ssum[wid] = local;
    __syncthreads();
    if (threadIdx.x == 0) out[0] = ssum[0] + ssum[1] + ssum[2] + ssum[3];
}

extern "C" void kernel_launch(void* const* d_in, const int* in_sizes, int n_in,
                              void* d_out, int out_size, void* d_ws, size_t ws_size,
                              hipStream_t stream) {
    const float* x0    = (const float*)d_in[0];
    const float* noise = (const float*)d_in[1];
    const float* Wm    = (const float*)d_in[2];
    const float* bias  = (const float*)d_in[3];
    const float* temb  = (const float*)d_in[4];
    const int*   t     = (const int*)d_in[5];
    float* out = (float*)d_out;
    float* ws  = (float*)d_ws;

    const int B = in_sizes[0] / (2 * 512 * 512);   // 32

    const int total  = B * 256 * 64;               // one thread per 4 output pixels
    const int blocks = total / 256;                // 2048

    fused_loss_kernel<<<blocks, 256, 0, stream>>>(x0, noise, Wm, bias, temb, t, ws);
    final_reduce_kernel<<<1, 256, 0, stream>>>(ws, out, blocks);
}